// Round 14
// baseline (155.930 us; speedup 1.0000x reference)
//
#include <hip/hip_runtime.h>

typedef __attribute__((ext_vector_type(4))) float f32x4;
typedef __attribute__((ext_vector_type(8))) short bf16x8;
typedef __attribute__((ext_vector_type(8))) unsigned short u16x8;
typedef __attribute__((ext_vector_type(4))) unsigned short u16x4;
typedef __attribute__((ext_vector_type(4))) unsigned int u32x4;
typedef unsigned short ushort_t;

#define LOG2E 1.4426950408889634f

__device__ inline unsigned short f2bf(float x) {
  union { float f; unsigned int u; } v; v.f = x;
  unsigned int r = v.u + 0x7fffu + ((v.u >> 16) & 1u);
  return (unsigned short)(r >> 16);
}

__device__ inline unsigned cvtpk_bf16(float a, float b) {
  unsigned r;
  asm("v_cvt_pk_bf16_f32 %0, %1, %2" : "=v"(r) : "v"(a), "v"(b));
  return r;
}

__device__ inline void gload_lds16(const void* g, void* l) {
  __builtin_amdgcn_global_load_lds(
      (const __attribute__((address_space(1))) unsigned int*)g,
      (__attribute__((address_space(3))) unsigned int*)l, 16, 0, 0);
}

// ---------------- f32 -> bf16 converts ----------------
__device__ inline void cvt_body(const float* __restrict__ src, ushort_t* __restrict__ dst, int i) {
  const f32x4* s = (const f32x4*)src;
  f32x4 a = s[2 * i], b = s[2 * i + 1];
  u16x8 o;
#pragma unroll
  for (int j = 0; j < 4; ++j) { o[j] = f2bf(a[j]); o[4 + j] = f2bf(b[j]); }
  *(u16x8*)(dst + (size_t)i * 8) = o;
}

__global__ __launch_bounds__(256) void cvt_bf16(const float* __restrict__ src,
                                                ushort_t* __restrict__ dst, int n8) {
  int i = blockIdx.x * 256 + threadIdx.x;
  if (i < n8) cvt_body(src, dst, i);
}

// One launch converts q,k,v (z=0..2) and all four weight matrices (z=3).
__global__ __launch_bounds__(256) void cvt_all(const float* __restrict__ q,
                                               const float* __restrict__ k,
                                               const float* __restrict__ v,
                                               const float* __restrict__ Wq,
                                               const float* __restrict__ Wk,
                                               const float* __restrict__ Wv,
                                               const float* __restrict__ Wo,
                                               ushort_t* __restrict__ Xb,
                                               ushort_t* __restrict__ Wb, int nx8) {
  int i = blockIdx.x * 256 + threadIdx.x;
  int z = blockIdx.y;
  if (z < 3) {
    if (i < nx8) cvt_body(z == 0 ? q : (z == 1 ? k : v), Xb + (size_t)z * nx8 * 8, i);
  } else {
    int w = i >> 17, off = i & 131071;  // 4 weights x 131072 i-units (1M elems each)
    const float* s = w == 0 ? Wq : (w == 1 ? Wk : (w == 2 ? Wv : Wo));
    cvt_body(s, Wb + (size_t)w * 1048576, off);
  }
}

// ---------------- shared GEMM tile core (BK=64, single-buffer) ----------------
template <typename F>
__device__ inline void gemm_core64(const ushort_t* __restrict__ A, const ushort_t* __restrict__ W,
                                   int m0, int n0, ushort_t* As, ushort_t* Bs, F&& mfma_step) {
  constexpr int K = 1024;
  const int tid = threadIdx.x, lane = tid & 63, wid = tid >> 6;
  const int r8 = lane >> 3;
  const int p8 = lane & 7;
  const int scol = (p8 ^ r8) * 8;
  for (int k0 = 0; k0 < K; k0 += 64) {
#pragma unroll
    for (int c = 0; c < 4; ++c) {
      int i = wid * 4 + c;
      int row = i * 8 + r8;
      gload_lds16(A + (size_t)(m0 + row) * K + k0 + scol, &As[i * 512]);
      gload_lds16(W + (size_t)(n0 + row) * K + k0 + scol, &Bs[i * 512]);
    }
    __syncthreads();
    mfma_step(As, Bs);
    __syncthreads();
  }
}

// ---------------- projection GEMM (z = 0:Q, 1:K, 2:V) ----------------
// XCD-bijective block remap: bid=(by*32+bx) -> swz=(bid&7)*32+(bid>>3).
// Pure permutation of [0,256) -> correctness independent of dispatch; gives
// each XCD one contiguous n-panel row (B-panel L2 locality).
__global__ __launch_bounds__(256) void proj_gemm(const ushort_t* __restrict__ Abase, int aStride,
                                                 const ushort_t* __restrict__ Wall, int wStride,
                                                 const float* __restrict__ bq,
                                                 const float* __restrict__ bk,
                                                 const float* __restrict__ bv, float qs,
                                                 ushort_t* __restrict__ outQ,
                                                 ushort_t* __restrict__ outK,
                                                 ushort_t* __restrict__ outV, int zofs) {
  __shared__ __attribute__((aligned(16))) ushort_t As[128 * 64];
  __shared__ __attribute__((aligned(16))) ushort_t Bs[128 * 64];
  const int z = blockIdx.z + zofs;
  const ushort_t* A = Abase + (size_t)z * aStride;
  const ushort_t* W = Wall + (size_t)z * wStride;
  const float* bias = z == 0 ? bq : (z == 1 ? bk : bv);
  const float scale = z == 0 ? qs : 1.0f;
  ushort_t* out = z == 0 ? outQ : (z == 1 ? outK : outV);
  const int mode = z == 2 ? 1 : 0;

  const int tid = threadIdx.x, lane = tid & 63, wid = tid >> 6;
  const int bid = blockIdx.y * 32 + blockIdx.x;
  const int swz = (bid & 7) * 32 + (bid >> 3);
  const int m0 = (swz & 31) * 128, n0 = (swz >> 5) * 128;
  const int wm = wid >> 1, wn = wid & 1;
  const int qr = lane & 15, kq = lane >> 4;
  f32x4 acc[4][4] = {};

  gemm_core64(A, W, m0, n0, As, Bs, [&](ushort_t* as, ushort_t* bs) {
#pragma unroll
    for (int h = 0; h < 2; ++h) {
      bf16x8 a[4], b[4];
#pragma unroll
      for (int f = 0; f < 4; ++f) {
        int ra = wm * 64 + f * 16 + qr;
        a[f] = *(const bf16x8*)&as[ra * 64 + (((h * 4 + kq) ^ (ra & 7)) * 8)];
        int rb = wn * 64 + f * 16 + qr;
        b[f] = *(const bf16x8*)&bs[rb * 64 + (((h * 4 + kq) ^ (rb & 7)) * 8)];
      }
#pragma unroll
      for (int i = 0; i < 4; ++i)
#pragma unroll
        for (int j = 0; j < 4; ++j)
          acc[i][j] = __builtin_amdgcn_mfma_f32_16x16x32_bf16(a[i], b[j], acc[i][j], 0, 0, 0);
    }
  });

  const int cm = m0 + wm * 64, cn = n0 + wn * 64;
#pragma unroll
  for (int fn = 0; fn < 4; ++fn) {
    int n = cn + fn * 16 + qr;
    float bvv = bias[n];
    int h = n >> 6, hd = n & 63;
#pragma unroll
    for (int fm = 0; fm < 4; ++fm) {
      int m = cm + fm * 16 + kq * 4;
      if (mode == 0) {
#pragma unroll
        for (int r = 0; r < 4; ++r) {
          int mm = m + r, b = mm >> 11, s = mm & 2047;
          out[((size_t)(b * 16 + h) * 2048 + s) * 64 + hd] = f2bf((acc[fm][fn][r] + bvv) * scale);
        }
      } else {
        int b = m >> 11, s = m & 2047;
        u16x4 pk;
#pragma unroll
        for (int r = 0; r < 4; ++r) pk[r] = f2bf((acc[fm][fn][r] + bvv) * scale);
        *(u16x4*)&out[((size_t)(b * 16 + h) * 64 + hd) * 2048 + s] = pk;
      }
    }
  }
}

// ---------------- output GEMM: f32 out = ctx * Wo^T + bo ----------------
__global__ __launch_bounds__(256) void gemm_out(const ushort_t* __restrict__ A,
                                                const ushort_t* __restrict__ W,
                                                const float* __restrict__ bias,
                                                float* __restrict__ out) {
  __shared__ __attribute__((aligned(16))) ushort_t As[128 * 64];
  __shared__ __attribute__((aligned(16))) ushort_t Bs[128 * 64];
  const int tid = threadIdx.x, lane = tid & 63, wid = tid >> 6;
  const int bid = blockIdx.y * 32 + blockIdx.x;
  const int swz = (bid & 7) * 32 + (bid >> 3);
  const int m0 = (swz & 31) * 128, n0 = (swz >> 5) * 128;
  const int wm = wid >> 1, wn = wid & 1;
  const int qr = lane & 15, kq = lane >> 4;
  f32x4 acc[4][4] = {};

  gemm_core64(A, W, m0, n0, As, Bs, [&](ushort_t* as, ushort_t* bs) {
#pragma unroll
    for (int h = 0; h < 2; ++h) {
      bf16x8 a[4], b[4];
#pragma unroll
      for (int f = 0; f < 4; ++f) {
        int ra = wm * 64 + f * 16 + qr;
        a[f] = *(const bf16x8*)&as[ra * 64 + (((h * 4 + kq) ^ (ra & 7)) * 8)];
        int rb = wn * 64 + f * 16 + qr;
        b[f] = *(const bf16x8*)&bs[rb * 64 + (((h * 4 + kq) ^ (rb & 7)) * 8)];
      }
#pragma unroll
      for (int i = 0; i < 4; ++i)
#pragma unroll
        for (int j = 0; j < 4; ++j)
          acc[i][j] = __builtin_amdgcn_mfma_f32_16x16x32_bf16(a[i], b[j], acc[i][j], 0, 0, 0);
    }
  });

  const int cm = m0 + wm * 64, cn = n0 + wn * 64;
#pragma unroll
  for (int fn = 0; fn < 4; ++fn) {
    int n = cn + fn * 16 + qr;
    float bvv = bias[n];
#pragma unroll
    for (int fm = 0; fm < 4; ++fm) {
      int m = cm + fm * 16 + kq * 4;
#pragma unroll
      for (int r = 0; r < 4; ++r) out[(size_t)(m + r) * 1024 + n] = acc[fm][fn][r] + bvv;
    }
  }
}

// ---------------- fused flash attention (R8-proven, byte-identical) ----------
// Swapped-operand QK^T, in-register P via cvt_pk + permlane pair-swaps,
// defer-max, K+V LDS double-buffer, shfl_xor row max and sum (PROVEN).
// Max-butterfly via self-permlane is BANNED: two equal-valued "+v" operands
// can coalesce to one register -> self-swap != max (R12/R13 failures).
__global__ __launch_bounds__(256) void attn_fwd(const ushort_t* __restrict__ Qh,
                                                const ushort_t* __restrict__ Kh,
                                                const ushort_t* __restrict__ Vt,
                                                ushort_t* __restrict__ ctx) {
  constexpr int S = 2048, HD = 64, NT = S / 64;
  __shared__ __attribute__((aligned(16))) ushort_t Ks[2][64 * 64];  // [buf][kv][hd] swz
  __shared__ __attribute__((aligned(16))) ushort_t Vs[2][64 * 64];  // [buf][hd][kv] swz

  const int tid = threadIdx.x, lane = tid & 63, wid = tid >> 6;
  const int bh = blockIdx.y, qt = blockIdx.x;
  const size_t head = (size_t)bh * S * HD;
  const ushort_t* Qp = Qh + head;
  const ushort_t* Kp = Kh + head;
  const ushort_t* Vp = Vt + head;

  const int qr = lane & 15, kq = lane >> 4;
  const int q0 = qt * 64 + wid * 16;

  bf16x8 qf[2];
  qf[0] = *(const bf16x8*)&Qp[(size_t)(q0 + qr) * HD + kq * 8];
  qf[1] = *(const bf16x8*)&Qp[(size_t)(q0 + qr) * HD + 32 + kq * 8];

  f32x4 accO[4] = {};
  float mrun = -3e38f, lrun = 0.f;

  const int srow8 = lane >> 3, sp8 = lane & 7;

  for (int t = 0; t < NT; ++t) {
    const int buf = t & 1;
    {
      int kv0 = t == 0 ? 0 : (t + 1) * 64;
      int dbuf = t == 0 ? 0 : buf ^ 1;
      if (t == 0 || t + 1 < NT) {
#pragma unroll
        for (int c = 0; c < 2; ++c) {
          int i = wid * 2 + c;
          int row = i * 8 + srow8;
          int s = sp8 ^ (row & 7);
          gload_lds16(&Kp[(size_t)(kv0 + row) * HD + s * 8], &Ks[dbuf][i * 512]);
          gload_lds16(&Vp[(size_t)row * S + kv0 + s * 8], &Vs[dbuf][i * 512]);
        }
      }
      if (t == 0) {
        __syncthreads();
        if (NT > 1) {
#pragma unroll
          for (int c = 0; c < 2; ++c) {
            int i = wid * 2 + c;
            int row = i * 8 + srow8;
            int s = sp8 ^ (row & 7);
            gload_lds16(&Kp[(size_t)(64 + row) * HD + s * 8], &Ks[1][i * 512]);
            gload_lds16(&Vp[(size_t)row * S + 64 + s * 8], &Vs[1][i * 512]);
          }
        }
      }
    }

    // ---- QK^T (swapped): sc[fn][r] = S[kv = fn*16+kq*4+r][q = qr]
    f32x4 sc[4] = {};
    __builtin_amdgcn_s_setprio(1);
#pragma unroll
    for (int fn = 0; fn < 4; ++fn) {
      int rk = fn * 16 + qr;
#pragma unroll
      for (int kh = 0; kh < 2; ++kh) {
        bf16x8 kf = *(const bf16x8*)&Ks[buf][rk * 64 + (((kh * 4 + kq) ^ (rk & 7)) * 8)];
        sc[fn] = __builtin_amdgcn_mfma_f32_16x16x32_bf16(kf, qf[kh], sc[fn], 0, 0, 0);
      }
    }
    __builtin_amdgcn_s_setprio(0);

    // ---- row max, cross-kq via 2 shfl (PROVEN)
    float t0 = fmaxf(fmaxf(fmaxf(sc[0][0], sc[0][1]), sc[0][2]), sc[0][3]);
    float t1 = fmaxf(fmaxf(fmaxf(sc[1][0], sc[1][1]), sc[1][2]), sc[1][3]);
    float t2 = fmaxf(fmaxf(fmaxf(sc[2][0], sc[2][1]), sc[2][2]), sc[2][3]);
    float t3 = fmaxf(fmaxf(fmaxf(sc[3][0], sc[3][1]), sc[3][2]), sc[3][3]);
    float pm = fmaxf(fmaxf(t0, t1), fmaxf(t2, t3));
    pm = fmaxf(pm, __shfl_xor(pm, 16, 64));
    pm = fmaxf(pm, __shfl_xor(pm, 32, 64));

    // ---- defer-max (exp2 domain, THR=8 -> P <= 256)
    bool need = pm > mrun + 8.0f;
    if (__any(need)) {
      float mn = need ? pm : mrun;
      float sf = __builtin_amdgcn_exp2f(mrun - mn);
      mrun = mn;
#pragma unroll
      for (int f2 = 0; f2 < 4; ++f2) accO[f2] *= sf;
      lrun *= sf;
    }

    // ---- P = exp2(sc - mrun); f32 row-sum; pack to bf16 pairs in-register
    float pv[4][4];
    float sum = 0.f;
#pragma unroll
    for (int fn = 0; fn < 4; ++fn)
#pragma unroll
      for (int r = 0; r < 4; ++r) {
        float p = __builtin_amdgcn_exp2f(sc[fn][r] - mrun);
        pv[fn][r] = p;
        sum += p;
      }
    sum += __shfl_xor(sum, 16, 64);
    sum += __shfl_xor(sum, 32, 64);
    lrun += sum;

    unsigned wv[4][2];
#pragma unroll
    for (int fn = 0; fn < 4; ++fn) {
      wv[fn][0] = cvtpk_bf16(pv[fn][0], pv[fn][1]);
      wv[fn][1] = cvtpk_bf16(pv[fn][2], pv[fn][3]);
    }

    // ---- PV (swapped): accO[hd][q] += V^T[hd][kv] * P^T[kv][q]
    __builtin_amdgcn_s_setprio(1);
#pragma unroll
    for (int ks = 0; ks < 2; ++ks) {
      unsigned a0 = wv[2 * ks][0], b0 = wv[2 * ks + 1][0];
      unsigned a1 = wv[2 * ks][1], b1 = wv[2 * ks + 1][1];
      asm volatile("v_permlane32_swap_b32 %0, %1" : "+v"(a0), "+v"(b0));
      asm volatile("v_permlane16_swap_b32 %0, %1" : "+v"(a0), "+v"(b0));
      asm volatile("v_permlane32_swap_b32 %0, %1" : "+v"(a1), "+v"(b1));
      asm volatile("v_permlane16_swap_b32 %0, %1" : "+v"(a1), "+v"(b1));
      u32x4 praw;
      praw[0] = a0; praw[1] = a1; praw[2] = b0; praw[3] = b1;
      bf16x8 pf = __builtin_bit_cast(bf16x8, praw);
#pragma unroll
      for (int f2 = 0; f2 < 4; ++f2) {
        int rv = f2 * 16 + qr;
        bf16x8 vf = *(const bf16x8*)&Vs[buf][rv * 64 + (((ks * 4 + kq) ^ (rv & 7)) * 8)];
        accO[f2] = __builtin_amdgcn_mfma_f32_16x16x32_bf16(vf, pf, accO[f2], 0, 0, 0);
      }
    }
    __builtin_amdgcn_s_setprio(0);
    __syncthreads();
  }

  float inv = 1.0f / lrun;
  const int b = bh >> 4, h = bh & 15;
#pragma unroll
  for (int f2 = 0; f2 < 4; ++f2) {
    u16x4 pk;
#pragma unroll
    for (int r = 0; r < 4; ++r) pk[r] = f2bf(accO[f2][r] * inv);
    int col = h * 64 + f2 * 16 + kq * 4;
    *(u16x4*)&ctx[((size_t)b * 2048 + q0 + qr) * 1024 + col] = pk;
  }
}

// ---------------- launch ----------------
extern "C" void kernel_launch(void* const* d_in, const int* in_sizes, int n_in,
                              void* d_out, int out_size, void* d_ws, size_t ws_size,
                              hipStream_t stream) {
  const float* q = (const float*)d_in[0];
  const float* k = (const float*)d_in[1];
  const float* v = (const float*)d_in[2];
  const float* Wq = (const float*)d_in[3];
  const float* bq = (const float*)d_in[4];
  const float* Wk = (const float*)d_in[5];
  const float* bk = (const float*)d_in[6];
  const float* Wv = (const float*)d_in[7];
  const float* bv = (const float*)d_in[8];
  const float* Wo = (const float*)d_in[9];
  const float* bo = (const float*)d_in[10];

  char* ws = (char*)d_ws;
  const size_t MB = 1024 * 1024;
  const int NXE = 4194304;
  const int NWE = 1048576;
  const float qs = 0.125f * LOG2E;
  dim3 gg(32, 8), ga(32, 32);

  if (ws_size >= 56 * MB) {
    ushort_t* Xb = (ushort_t*)(ws);
    ushort_t* Wb = (ushort_t*)(ws + 24 * MB);
    ushort_t* Qh = (ushort_t*)(ws + 32 * MB);
    ushort_t* Kh = (ushort_t*)(ws + 40 * MB);
    ushort_t* Vt = (ushort_t*)(ws + 48 * MB);
    cvt_all<<<dim3(2048, 4), 256, 0, stream>>>(q, k, v, Wq, Wk, Wv, Wo, Xb, Wb, NXE / 8);
    proj_gemm<<<dim3(32, 8, 3), 256, 0, stream>>>(Xb, NXE, Wb, NWE, bq, bk, bv, qs,
                                                  Qh, Kh, Vt, 0);
    attn_fwd<<<ga, 256, 0, stream>>>(Qh, Kh, Vt, Xb);
    gemm_out<<<gg, 256, 0, stream>>>(Xb, Wb + (size_t)3 * NWE, bo, (float*)d_out);
  } else if (ws_size >= 40 * MB) {
    ushort_t* Xb = (ushort_t*)(ws);
    ushort_t* Wb = (ushort_t*)(ws + 8 * MB);
    ushort_t* Qh = (ushort_t*)(ws + 16 * MB);
    ushort_t* Kh = (ushort_t*)(ws + 24 * MB);
    ushort_t* Vt = (ushort_t*)(ws + 32 * MB);
    const float* xs[3] = {q, k, v};
    for (int z = 0; z < 3; ++z) {
      cvt_bf16<<<2048, 256, 0, stream>>>(xs[z], Xb, NXE / 8);
      if (z == 0)
        cvt_all<<<dim3(2048, 1), 256, 0, stream>>>(q, k, v, Wq, Wk, Wv, Wo, Xb, Wb, 0);
      proj_gemm<<<dim3(32, 8, 1), 256, 0, stream>>>(Xb, 0, Wb, NWE, bq, bk, bv, qs,
                                                    Qh, Kh, Vt, z);
    }
    attn_fwd<<<ga, 256, 0, stream>>>(Qh, Kh, Vt, Xb);
    gemm_out<<<gg, 256, 0, stream>>>(Xb, Wb + (size_t)3 * NWE, bo, (float*)d_out);
  } else {
    ushort_t* Xb = (ushort_t*)(ws);
    ushort_t* Wb = (ushort_t*)(ws + 8 * MB);
    ushort_t* Qh = (ushort_t*)(ws + 10 * MB);
    ushort_t* Kh = (ushort_t*)(ws + 18 * MB);
    ushort_t* Vt = (ushort_t*)(ws + 26 * MB);
    const float* xs[3] = {q, k, v};
    const float* wsrc[3] = {Wq, Wk, Wv};
    for (int z = 0; z < 3; ++z) {
      cvt_bf16<<<2048, 256, 0, stream>>>(xs[z], Xb, NXE / 8);
      cvt_bf16<<<512, 256, 0, stream>>>(wsrc[z], Wb, NWE / 8);
      proj_gemm<<<dim3(32, 8, 1), 256, 0, stream>>>(Xb, 0, Wb, 0, bq, bk, bv, qs,
                                                    Qh, Kh, Vt, z);
    }
    attn_fwd<<<ga, 256, 0, stream>>>(Qh, Kh, Vt, Xb);
    cvt_bf16<<<512, 256, 0, stream>>>(Wo, Wb, NWE / 8);
    gemm_out<<<gg, 256, 0, stream>>>(Xb, Wb, bo, (float*)d_out);
  }
}

// Round 15
// 141.355 us; speedup vs baseline: 1.1031x; 1.1031x over previous
//
#include <hip/hip_runtime.h>

typedef __attribute__((ext_vector_type(4))) float f32x4;
typedef __attribute__((ext_vector_type(8))) short bf16x8;
typedef __attribute__((ext_vector_type(8))) unsigned short u16x8;
typedef __attribute__((ext_vector_type(4))) unsigned short u16x4;
typedef __attribute__((ext_vector_type(4))) unsigned int u32x4;
typedef unsigned short ushort_t;

#define LOG2E 1.4426950408889634f

__device__ inline unsigned short f2bf(float x) {
  union { float f; unsigned int u; } v; v.f = x;
  unsigned int r = v.u + 0x7fffu + ((v.u >> 16) & 1u);
  return (unsigned short)(r >> 16);
}

__device__ inline unsigned cvtpk_bf16(float a, float b) {
  unsigned r;
  asm("v_cvt_pk_bf16_f32 %0, %1, %2" : "=v"(r) : "v"(a), "v"(b));
  return r;
}

__device__ inline void gload_lds16(const void* g, void* l) {
  __builtin_amdgcn_global_load_lds(
      (const __attribute__((address_space(1))) unsigned int*)g,
      (__attribute__((address_space(3))) unsigned int*)l, 16, 0, 0);
}

// ---------------- f32 -> bf16 converts ----------------
__device__ inline void cvt_body(const float* __restrict__ src, ushort_t* __restrict__ dst, int i) {
  const f32x4* s = (const f32x4*)src;
  f32x4 a = s[2 * i], b = s[2 * i + 1];
  u16x8 o;
#pragma unroll
  for (int j = 0; j < 4; ++j) { o[j] = f2bf(a[j]); o[4 + j] = f2bf(b[j]); }
  *(u16x8*)(dst + (size_t)i * 8) = o;
}

__global__ __launch_bounds__(256) void cvt_bf16(const float* __restrict__ src,
                                                ushort_t* __restrict__ dst, int n8) {
  int i = blockIdx.x * 256 + threadIdx.x;
  if (i < n8) cvt_body(src, dst, i);
}

// One launch converts q,k,v (z=0..2) and all four weight matrices (z=3).
__global__ __launch_bounds__(256) void cvt_all(const float* __restrict__ q,
                                               const float* __restrict__ k,
                                               const float* __restrict__ v,
                                               const float* __restrict__ Wq,
                                               const float* __restrict__ Wk,
                                               const float* __restrict__ Wv,
                                               const float* __restrict__ Wo,
                                               ushort_t* __restrict__ Xb,
                                               ushort_t* __restrict__ Wb, int nx8) {
  int i = blockIdx.x * 256 + threadIdx.x;
  int z = blockIdx.y;
  if (z < 3) {
    if (i < nx8) cvt_body(z == 0 ? q : (z == 1 ? k : v), Xb + (size_t)z * nx8 * 8, i);
  } else {
    int w = i >> 17, off = i & 131071;  // 4 weights x 131072 i-units (1M elems each)
    const float* s = w == 0 ? Wq : (w == 1 ? Wk : (w == 2 ? Wv : Wo));
    cvt_body(s, Wb + (size_t)w * 1048576, off);
  }
}

// ---------------- shared GEMM tile core ----------------
// BK=32, DOUBLE-BUFFERED: stage(k+1) issued BEFORE compute(k); one barrier per
// K-step (drains staging via the barrier's vmcnt(0) + guards buffer reuse).
// Identical loop shape to the attention kernel's proven K/V pipeline.
// Staging/read swizzle indices are R1-R7's proven BK=32 pattern.
template <typename F>
__device__ inline void gemm_core32(const ushort_t* __restrict__ A, const ushort_t* __restrict__ W,
                                   int m0, int n0,
                                   ushort_t (&As)[2][128 * 32], ushort_t (&Bs)[2][128 * 32],
                                   F&& mfma_step) {
  constexpr int K = 1024;
  const int tid = threadIdx.x, lane = tid & 63, wid = tid >> 6;
  const int srow = lane >> 2;  // row within 16-row chunk
  const int sp = lane & 3;     // physical 16B slot

  auto stage = [&](int k0, int db) {
#pragma unroll
    for (int c = 0; c < 2; ++c) {
      int i = wid * 2 + c;
      int row = i * 16 + srow;
      int s = sp ^ ((row >> 1) & 3);
      gload_lds16(A + (size_t)(m0 + row) * K + k0 + s * 8, &As[db][i * 512]);
      gload_lds16(W + (size_t)(n0 + row) * K + k0 + s * 8, &Bs[db][i * 512]);
    }
  };

  stage(0, 0);
  __syncthreads();
  for (int k0 = 0; k0 < K; k0 += 32) {
    const int buf = (k0 >> 5) & 1;
    if (k0 + 32 < K) stage(k0 + 32, buf ^ 1);  // in flight across compute(k)
    mfma_step(As[buf], Bs[buf]);
    __syncthreads();  // drains next-tile staging; guards buf reuse
  }
}

// ---------------- projection GEMM (z = 0:Q, 1:K, 2:V) ----------------
__global__ __launch_bounds__(256) void proj_gemm(const ushort_t* __restrict__ Abase, int aStride,
                                                 const ushort_t* __restrict__ Wall, int wStride,
                                                 const float* __restrict__ bq,
                                                 const float* __restrict__ bk,
                                                 const float* __restrict__ bv, float qs,
                                                 ushort_t* __restrict__ outQ,
                                                 ushort_t* __restrict__ outK,
                                                 ushort_t* __restrict__ outV, int zofs) {
  __shared__ __attribute__((aligned(16))) ushort_t As[2][128 * 32];
  __shared__ __attribute__((aligned(16))) ushort_t Bs[2][128 * 32];
  const int z = blockIdx.z + zofs;
  const ushort_t* A = Abase + (size_t)z * aStride;
  const ushort_t* W = Wall + (size_t)z * wStride;
  const float* bias = z == 0 ? bq : (z == 1 ? bk : bv);
  const float scale = z == 0 ? qs : 1.0f;
  ushort_t* out = z == 0 ? outQ : (z == 1 ? outK : outV);
  const int mode = z == 2 ? 1 : 0;

  const int tid = threadIdx.x, lane = tid & 63, wid = tid >> 6;
  const int m0 = blockIdx.x * 128, n0 = blockIdx.y * 128;
  const int wm = wid >> 1, wn = wid & 1;
  const int qr = lane & 15, kq = lane >> 4;
  f32x4 acc[4][4] = {};

  gemm_core32(A, W, m0, n0, As, Bs, [&](ushort_t* as, ushort_t* bs) {
    bf16x8 a[4], b[4];
#pragma unroll
    for (int f = 0; f < 4; ++f) {
      int ra = wm * 64 + f * 16 + qr;
      a[f] = *(const bf16x8*)&as[ra * 32 + (kq ^ ((ra >> 1) & 3)) * 8];
      int rb = wn * 64 + f * 16 + qr;
      b[f] = *(const bf16x8*)&bs[rb * 32 + (kq ^ ((rb >> 1) & 3)) * 8];
    }
#pragma unroll
    for (int i = 0; i < 4; ++i)
#pragma unroll
      for (int j = 0; j < 4; ++j)
        acc[i][j] = __builtin_amdgcn_mfma_f32_16x16x32_bf16(a[i], b[j], acc[i][j], 0, 0, 0);
  });

  const int cm = m0 + wm * 64, cn = n0 + wn * 64;
#pragma unroll
  for (int fn = 0; fn < 4; ++fn) {
    int n = cn + fn * 16 + qr;
    float bvv = bias[n];
    int h = n >> 6, hd = n & 63;
#pragma unroll
    for (int fm = 0; fm < 4; ++fm) {
      int m = cm + fm * 16 + kq * 4;
      if (mode == 0) {
#pragma unroll
        for (int r = 0; r < 4; ++r) {
          int mm = m + r, b = mm >> 11, s = mm & 2047;
          out[((size_t)(b * 16 + h) * 2048 + s) * 64 + hd] = f2bf((acc[fm][fn][r] + bvv) * scale);
        }
      } else {
        int b = m >> 11, s = m & 2047;
        u16x4 pk;
#pragma unroll
        for (int r = 0; r < 4; ++r) pk[r] = f2bf((acc[fm][fn][r] + bvv) * scale);
        *(u16x4*)&out[((size_t)(b * 16 + h) * 64 + hd) * 2048 + s] = pk;
      }
    }
  }
}

// ---------------- output GEMM: f32 out = ctx * Wo^T + bo ----------------
__global__ __launch_bounds__(256) void gemm_out(const ushort_t* __restrict__ A,
                                                const ushort_t* __restrict__ W,
                                                const float* __restrict__ bias,
                                                float* __restrict__ out) {
  __shared__ __attribute__((aligned(16))) ushort_t As[2][128 * 32];
  __shared__ __attribute__((aligned(16))) ushort_t Bs[2][128 * 32];
  const int tid = threadIdx.x, lane = tid & 63, wid = tid >> 6;
  const int m0 = blockIdx.x * 128, n0 = blockIdx.y * 128;
  const int wm = wid >> 1, wn = wid & 1;
  const int qr = lane & 15, kq = lane >> 4;
  f32x4 acc[4][4] = {};

  gemm_core32(A, W, m0, n0, As, Bs, [&](ushort_t* as, ushort_t* bs) {
    bf16x8 a[4], b[4];
#pragma unroll
    for (int f = 0; f < 4; ++f) {
      int ra = wm * 64 + f * 16 + qr;
      a[f] = *(const bf16x8*)&as[ra * 32 + (kq ^ ((ra >> 1) & 3)) * 8];
      int rb = wn * 64 + f * 16 + qr;
      b[f] = *(const bf16x8*)&bs[rb * 32 + (kq ^ ((rb >> 1) & 3)) * 8];
    }
#pragma unroll
    for (int i = 0; i < 4; ++i)
#pragma unroll
      for (int j = 0; j < 4; ++j)
        acc[i][j] = __builtin_amdgcn_mfma_f32_16x16x32_bf16(a[i], b[j], acc[i][j], 0, 0, 0);
  });

  const int cm = m0 + wm * 64, cn = n0 + wn * 64;
#pragma unroll
  for (int fn = 0; fn < 4; ++fn) {
    int n = cn + fn * 16 + qr;
    float bvv = bias[n];
#pragma unroll
    for (int fm = 0; fm < 4; ++fm) {
      int m = cm + fm * 16 + kq * 4;
#pragma unroll
      for (int r = 0; r < 4; ++r) out[(size_t)(m + r) * 1024 + n] = acc[fm][fn][r] + bvv;
    }
  }
}

// ---------------- fused flash attention (R8-proven, byte-identical) ----------
__global__ __launch_bounds__(256) void attn_fwd(const ushort_t* __restrict__ Qh,
                                                const ushort_t* __restrict__ Kh,
                                                const ushort_t* __restrict__ Vt,
                                                ushort_t* __restrict__ ctx) {
  constexpr int S = 2048, HD = 64, NT = S / 64;
  __shared__ __attribute__((aligned(16))) ushort_t Ks[2][64 * 64];  // [buf][kv][hd] swz
  __shared__ __attribute__((aligned(16))) ushort_t Vs[2][64 * 64];  // [buf][hd][kv] swz

  const int tid = threadIdx.x, lane = tid & 63, wid = tid >> 6;
  const int bh = blockIdx.y, qt = blockIdx.x;
  const size_t head = (size_t)bh * S * HD;
  const ushort_t* Qp = Qh + head;
  const ushort_t* Kp = Kh + head;
  const ushort_t* Vp = Vt + head;

  const int qr = lane & 15, kq = lane >> 4;
  const int q0 = qt * 64 + wid * 16;

  bf16x8 qf[2];
  qf[0] = *(const bf16x8*)&Qp[(size_t)(q0 + qr) * HD + kq * 8];
  qf[1] = *(const bf16x8*)&Qp[(size_t)(q0 + qr) * HD + 32 + kq * 8];

  f32x4 accO[4] = {};
  float mrun = -3e38f, lrun = 0.f;

  const int srow8 = lane >> 3, sp8 = lane & 7;

  for (int t = 0; t < NT; ++t) {
    const int buf = t & 1;
    {
      int kv0 = t == 0 ? 0 : (t + 1) * 64;
      int dbuf = t == 0 ? 0 : buf ^ 1;
      if (t == 0 || t + 1 < NT) {
#pragma unroll
        for (int c = 0; c < 2; ++c) {
          int i = wid * 2 + c;
          int row = i * 8 + srow8;
          int s = sp8 ^ (row & 7);
          gload_lds16(&Kp[(size_t)(kv0 + row) * HD + s * 8], &Ks[dbuf][i * 512]);
          gload_lds16(&Vp[(size_t)row * S + kv0 + s * 8], &Vs[dbuf][i * 512]);
        }
      }
      if (t == 0) {
        __syncthreads();
        if (NT > 1) {
#pragma unroll
          for (int c = 0; c < 2; ++c) {
            int i = wid * 2 + c;
            int row = i * 8 + srow8;
            int s = sp8 ^ (row & 7);
            gload_lds16(&Kp[(size_t)(64 + row) * HD + s * 8], &Ks[1][i * 512]);
            gload_lds16(&Vp[(size_t)row * S + 64 + s * 8], &Vs[1][i * 512]);
          }
        }
      }
    }

    // ---- QK^T (swapped): sc[fn][r] = S[kv = fn*16+kq*4+r][q = qr]
    f32x4 sc[4] = {};
    __builtin_amdgcn_s_setprio(1);
#pragma unroll
    for (int fn = 0; fn < 4; ++fn) {
      int rk = fn * 16 + qr;
#pragma unroll
      for (int kh = 0; kh < 2; ++kh) {
        bf16x8 kf = *(const bf16x8*)&Ks[buf][rk * 64 + (((kh * 4 + kq) ^ (rk & 7)) * 8)];
        sc[fn] = __builtin_amdgcn_mfma_f32_16x16x32_bf16(kf, qf[kh], sc[fn], 0, 0, 0);
      }
    }
    __builtin_amdgcn_s_setprio(0);

    // ---- row max, cross-kq via 2 shfl (PROVEN)
    float t0 = fmaxf(fmaxf(fmaxf(sc[0][0], sc[0][1]), sc[0][2]), sc[0][3]);
    float t1 = fmaxf(fmaxf(fmaxf(sc[1][0], sc[1][1]), sc[1][2]), sc[1][3]);
    float t2 = fmaxf(fmaxf(fmaxf(sc[2][0], sc[2][1]), sc[2][2]), sc[2][3]);
    float t3 = fmaxf(fmaxf(fmaxf(sc[3][0], sc[3][1]), sc[3][2]), sc[3][3]);
    float pm = fmaxf(fmaxf(t0, t1), fmaxf(t2, t3));
    pm = fmaxf(pm, __shfl_xor(pm, 16, 64));
    pm = fmaxf(pm, __shfl_xor(pm, 32, 64));

    // ---- defer-max (exp2 domain, THR=8 -> P <= 256)
    bool need = pm > mrun + 8.0f;
    if (__any(need)) {
      float mn = need ? pm : mrun;
      float sf = __builtin_amdgcn_exp2f(mrun - mn);
      mrun = mn;
#pragma unroll
      for (int f2 = 0; f2 < 4; ++f2) accO[f2] *= sf;
      lrun *= sf;
    }

    // ---- P = exp2(sc - mrun); f32 row-sum; pack to bf16 pairs in-register
    float pv[4][4];
    float sum = 0.f;
#pragma unroll
    for (int fn = 0; fn < 4; ++fn)
#pragma unroll
      for (int r = 0; r < 4; ++r) {
        float p = __builtin_amdgcn_exp2f(sc[fn][r] - mrun);
        pv[fn][r] = p;
        sum += p;
      }
    sum += __shfl_xor(sum, 16, 64);
    sum += __shfl_xor(sum, 32, 64);
    lrun += sum;

    unsigned wv[4][2];
#pragma unroll
    for (int fn = 0; fn < 4; ++fn) {
      wv[fn][0] = cvtpk_bf16(pv[fn][0], pv[fn][1]);
      wv[fn][1] = cvtpk_bf16(pv[fn][2], pv[fn][3]);
    }

    // ---- PV (swapped): accO[hd][q] += V^T[hd][kv] * P^T[kv][q]
    __builtin_amdgcn_s_setprio(1);
#pragma unroll
    for (int ks = 0; ks < 2; ++ks) {
      unsigned a0 = wv[2 * ks][0], b0 = wv[2 * ks + 1][0];
      unsigned a1 = wv[2 * ks][1], b1 = wv[2 * ks + 1][1];
      asm volatile("v_permlane32_swap_b32 %0, %1" : "+v"(a0), "+v"(b0));
      asm volatile("v_permlane16_swap_b32 %0, %1" : "+v"(a0), "+v"(b0));
      asm volatile("v_permlane32_swap_b32 %0, %1" : "+v"(a1), "+v"(b1));
      asm volatile("v_permlane16_swap_b32 %0, %1" : "+v"(a1), "+v"(b1));
      u32x4 praw;
      praw[0] = a0; praw[1] = a1; praw[2] = b0; praw[3] = b1;
      bf16x8 pf = __builtin_bit_cast(bf16x8, praw);
#pragma unroll
      for (int f2 = 0; f2 < 4; ++f2) {
        int rv = f2 * 16 + qr;
        bf16x8 vf = *(const bf16x8*)&Vs[buf][rv * 64 + (((ks * 4 + kq) ^ (rv & 7)) * 8)];
        accO[f2] = __builtin_amdgcn_mfma_f32_16x16x32_bf16(vf, pf, accO[f2], 0, 0, 0);
      }
    }
    __builtin_amdgcn_s_setprio(0);
    __syncthreads();
  }

  float inv = 1.0f / lrun;
  const int b = bh >> 4, h = bh & 15;
#pragma unroll
  for (int f2 = 0; f2 < 4; ++f2) {
    u16x4 pk;
#pragma unroll
    for (int r = 0; r < 4; ++r) pk[r] = f2bf(accO[f2][r] * inv);
    int col = h * 64 + f2 * 16 + kq * 4;
    *(u16x4*)&ctx[((size_t)b * 2048 + q0 + qr) * 1024 + col] = pk;
  }
}

// ---------------- launch ----------------
extern "C" void kernel_launch(void* const* d_in, const int* in_sizes, int n_in,
                              void* d_out, int out_size, void* d_ws, size_t ws_size,
                              hipStream_t stream) {
  const float* q = (const float*)d_in[0];
  const float* k = (const float*)d_in[1];
  const float* v = (const float*)d_in[2];
  const float* Wq = (const float*)d_in[3];
  const float* bq = (const float*)d_in[4];
  const float* Wk = (const float*)d_in[5];
  const float* bk = (const float*)d_in[6];
  const float* Wv = (const float*)d_in[7];
  const float* bv = (const float*)d_in[8];
  const float* Wo = (const float*)d_in[9];
  const float* bo = (const float*)d_in[10];

  char* ws = (char*)d_ws;
  const size_t MB = 1024 * 1024;
  const int NXE = 4194304;
  const int NWE = 1048576;
  const float qs = 0.125f * LOG2E;
  dim3 gg(32, 8), ga(32, 32);

  if (ws_size >= 56 * MB) {
    ushort_t* Xb = (ushort_t*)(ws);
    ushort_t* Wb = (ushort_t*)(ws + 24 * MB);
    ushort_t* Qh = (ushort_t*)(ws + 32 * MB);
    ushort_t* Kh = (ushort_t*)(ws + 40 * MB);
    ushort_t* Vt = (ushort_t*)(ws + 48 * MB);
    cvt_all<<<dim3(2048, 4), 256, 0, stream>>>(q, k, v, Wq, Wk, Wv, Wo, Xb, Wb, NXE / 8);
    proj_gemm<<<dim3(32, 8, 3), 256, 0, stream>>>(Xb, NXE, Wb, NWE, bq, bk, bv, qs,
                                                  Qh, Kh, Vt, 0);
    attn_fwd<<<ga, 256, 0, stream>>>(Qh, Kh, Vt, Xb);
    gemm_out<<<gg, 256, 0, stream>>>(Xb, Wb + (size_t)3 * NWE, bo, (float*)d_out);
  } else if (ws_size >= 40 * MB) {
    ushort_t* Xb = (ushort_t*)(ws);
    ushort_t* Wb = (ushort_t*)(ws + 8 * MB);
    ushort_t* Qh = (ushort_t*)(ws + 16 * MB);
    ushort_t* Kh = (ushort_t*)(ws + 24 * MB);
    ushort_t* Vt = (ushort_t*)(ws + 32 * MB);
    const float* xs[3] = {q, k, v};
    for (int z = 0; z < 3; ++z) {
      cvt_bf16<<<2048, 256, 0, stream>>>(xs[z], Xb, NXE / 8);
      if (z == 0)
        cvt_all<<<dim3(2048, 1), 256, 0, stream>>>(q, k, v, Wq, Wk, Wv, Wo, Xb, Wb, 0);
      proj_gemm<<<dim3(32, 8, 1), 256, 0, stream>>>(Xb, 0, Wb, NWE, bq, bk, bv, qs,
                                                    Qh, Kh, Vt, z);
    }
    attn_fwd<<<ga, 256, 0, stream>>>(Qh, Kh, Vt, Xb);
    gemm_out<<<gg, 256, 0, stream>>>(Xb, Wb + (size_t)3 * NWE, bo, (float*)d_out);
  } else {
    ushort_t* Xb = (ushort_t*)(ws);
    ushort_t* Wb = (ushort_t*)(ws + 8 * MB);
    ushort_t* Qh = (ushort_t*)(ws + 10 * MB);
    ushort_t* Kh = (ushort_t*)(ws + 18 * MB);
    ushort_t* Vt = (ushort_t*)(ws + 26 * MB);
    const float* xs[3] = {q, k, v};
    const float* wsrc[3] = {Wq, Wk, Wv};
    for (int z = 0; z < 3; ++z) {
      cvt_bf16<<<2048, 256, 0, stream>>>(xs[z], Xb, NXE / 8);
      cvt_bf16<<<512, 256, 0, stream>>>(wsrc[z], Wb, NWE / 8);
      proj_gemm<<<dim3(32, 8, 1), 256, 0, stream>>>(Xb, 0, Wb, 0, bq, bk, bv, qs,
                                                    Qh, Kh, Vt, z);
    }
    attn_fwd<<<ga, 256, 0, stream>>>(Qh, Kh, Vt, Xb);
    cvt_bf16<<<512, 256, 0, stream>>>(Wo, Wb, NWE / 8);
    gemm_out<<<gg, 256, 0, stream>>>(Xb, Wb, bo, (float*)d_out);
  }
}